// Round 11
// baseline (557.260 us; speedup 1.0000x reference)
//
#include <hip/hip_runtime.h>

typedef _Float16 f16;
typedef f16  half8 __attribute__((ext_vector_type(8)));
typedef float f32x4 __attribute__((ext_vector_type(4)));

#define B_   32
#define C_   1024
#define HW_  784
#define BQ   64

// Fragment-packed workspace layouts (offsets in f16 elements) — r6 layout:
//  mA   [b][panel=c>>4][kc=0..23][lane]  half8 along k=kc*32+(lane>>4)*8, row c=panel*16+(lane&15)
//  tailA[b][panel][sl=0..1][l15]         half8 along k=768+sl*8 (valid lanes l4<2)
//  mV   [b][pd=d>>4 (49)][kt=kv>>5][lane] half8 along kv=kt*32+(lane>>4)*8, row d=pd*16+(lane&15)
//  P    [tile=b*16+rb][row 64][kv 1024]  plain row-major f16 (softmaxed probabilities)
#define MA_BATCH  786432ull        // 64*24*512
#define TA_OFF    25165824ull      // 32*MA_BATCH
#define TA_BATCH  16384ull         // 64*2*16*8
#define MV_OFF    25690112ull      // TA_OFF + 32*TA_BATCH
#define MV_BATCH  802816ull        // 49*32*512
#define P_OFF     51380224ull      // MV_OFF + 32*MV_BATCH  (== 102,760,448 bytes)
#define P_TILE    65536ull         // 64*1024 f16 per tile
// base ws  = P_OFF*2               = 102,760,448 bytes
// split ws = (P_OFF + 512*P_TILE)*2 = 169,869,312 bytes

// ---------------------------------------------------------------------------
// Prep: build mA / tailA / mV from x (f32 -> f16, fragment-packed). (r6)
// ---------------------------------------------------------------------------
__global__ __launch_bounds__(256)
void prep_kernel(const float* __restrict__ x, f16* __restrict__ ws) {
  __shared__ f16 lt[64][72];
  const int bi = blockIdx.x;               // b*208 + ct*13 + ht
  const int ht = bi % 13;
  const int ct = (bi / 13) & 15;
  const int b  = bi / 208;
  const int h0 = ht * 64, c0 = ct * 64;
  const int t = threadIdx.x, r = t >> 2, q = t & 3;

  f16* mA = ws + (size_t)b * MA_BATCH;
  f16* tA = ws + TA_OFF + (size_t)b * TA_BATCH;
  f16* mV = ws + MV_OFF + (size_t)b * MV_BATCH;

  const int c  = c0 + r;
  const int pc = c >> 4, cl = c & 15;
  const int hq = h0 + q * 16;
  if (hq < HW_) {
    const float* src = x + (size_t)b * (C_ * HW_) + (size_t)c * HW_ + hq;
    float f[16];
#pragma unroll
    for (int j = 0; j < 4; ++j) ((float4*)f)[j] = ((const float4*)src)[j];
    f16 h[16];
#pragma unroll
    for (int j = 0; j < 16; ++j) h[j] = (f16)f[j];
    if (hq < 768) {
      const int kc = hq >> 5;
      const int l4 = (hq >> 3) & 3;          // 0 or 2
      f16* d0 = mA + ((size_t)pc * 24 + kc) * 512 + ((l4    ) * 16 + cl) * 8;
      f16* d1 = mA + ((size_t)pc * 24 + kc) * 512 + ((l4 + 1) * 16 + cl) * 8;
      *(half8*)d0 = *(half8*)h;
      *(half8*)d1 = *(half8*)(h + 8);
    } else {                                  // hq == 768: tail chunk
      f16* d0 = tA + pc * 256 + cl * 8;
      f16* d1 = tA + pc * 256 + 128 + cl * 8;
      *(half8*)d0 = *(half8*)h;
      *(half8*)d1 = *(half8*)(h + 8);
    }
    *(half8*)&lt[r][q * 16]     = *(half8*)h;
    *(half8*)&lt[r][q * 16 + 8] = *(half8*)(h + 8);
  }
  __syncthreads();
  // transposed side -> mV (d = hw, kv = c)
  if (h0 + r < HW_) {
    f16 g[16];
#pragma unroll
    for (int j = 0; j < 16; ++j) g[j] = lt[q * 16 + j][r];
    const int d  = h0 + r;
    const int pd = d >> 4, dl = d & 15;
    const int kv = c0 + q * 16;
    const int kt = kv >> 5;
    const int l4 = (kv >> 3) & 3;            // 0 or 2
    f16* e0 = mV + ((size_t)pd * 32 + kt) * 512 + ((l4    ) * 16 + dl) * 8;
    f16* e1 = mV + ((size_t)pd * 32 + kt) * 512 + ((l4 + 1) * 16 + dl) * 8;
    *(half8*)e0 = *(half8*)g;
    *(half8*)e1 = *(half8*)(g + 8);
  }
}

// ---------------------------------------------------------------------------
// Kernel A: phase 1 (r6) + softmax; normalized P written to ws (row-major).
// ---------------------------------------------------------------------------
__global__ __launch_bounds__(1024, 4)
void chanattn_qk(const f16* __restrict__ ws, f16* __restrict__ pws) {
  __shared__ f16 Pl[BQ * C_];   // raw scores staging (128 KiB)
  char* Pb = (char*)Pl;

  const int bi   = blockIdx.x;
  const int slot = bi >> 3;
  const int b    = ((slot >> 4) << 3) | (bi & 7);   // same-batch WGs share an XCD
  const int rb   = slot & 15;
  const int q0   = rb * BQ;

  const int tid  = threadIdx.x;
  const int w    = tid >> 6;
  const int lane = tid & 63;
  const int l15  = lane & 15;
  const int l4   = lane >> 4;

  const f16* mA = ws + (size_t)b * MA_BATCH;
  const f16* tA = ws + TA_OFF + (size_t)b * TA_BATCH;
  const int pa = q0 >> 4;

  // ---------------- Phase 1 (identical to r6) ----------------
  {
    f32x4 acc[4][4] = {};
    for (int kc = 0; kc < 24; ++kc) {
      half8 afr[4], bfr[4];
#pragma unroll
      for (int rf = 0; rf < 4; ++rf)
        afr[rf] = *(const half8*)(mA + ((size_t)(pa + rf) * 24 + kc) * 512 + lane * 8);
#pragma unroll
      for (int cf = 0; cf < 4; ++cf)
        bfr[cf] = *(const half8*)(mA + ((size_t)(w * 4 + cf) * 24 + kc) * 512 + lane * 8);
#pragma unroll
      for (int rf = 0; rf < 4; ++rf)
#pragma unroll
        for (int cf = 0; cf < 4; ++cf)
          acc[rf][cf] = __builtin_amdgcn_mfma_f32_16x16x32_f16(afr[rf], bfr[cf], acc[rf][cf], 0, 0, 0);
    }
    { // tail chunk k=768..783 (zero for l4>=2)
      half8 afr[4], bfr[4];
#pragma unroll
      for (int rf = 0; rf < 4; ++rf) {
        half8 v = {};
        if (l4 < 2) v = *(const half8*)(tA + (pa + rf) * 256 + lane * 8);
        afr[rf] = v;
      }
#pragma unroll
      for (int cf = 0; cf < 4; ++cf) {
        half8 v = {};
        if (l4 < 2) v = *(const half8*)(tA + (w * 4 + cf) * 256 + lane * 8);
        bfr[cf] = v;
      }
#pragma unroll
      for (int rf = 0; rf < 4; ++rf)
#pragma unroll
        for (int cf = 0; cf < 4; ++cf)
          acc[rf][cf] = __builtin_amdgcn_mfma_f32_16x16x32_f16(afr[rf], bfr[cf], acc[rf][cf], 0, 0, 0);
    }
    // raw scores -> LDS (XOR swizzle)
#pragma unroll
    for (int rf = 0; rf < 4; ++rf)
#pragma unroll
      for (int cf = 0; cf < 4; ++cf)
#pragma unroll
        for (int r = 0; r < 4; ++r) {
          const int row = rf * 16 + l4 * 4 + r;
          const int col = w * 64 + cf * 16 + l15;
          int byte = row * 2048 + col * 2;
          byte ^= (row & 7) << 4;
          *(f16*)(Pb + byte) = (f16)acc[rf][cf][r];
        }
  }
  __syncthreads();

  // ---------------- softmax rows w*4..w*4+3; P -> ws (row-major) ----------------
  {
    const float ksc = 0.045084223f;   // log2(e)/32
    f16* ptile = pws + (size_t)(b * 16 + rb) * P_TILE;
    for (int rr = 0; rr < 4; ++rr) {
      const int row = w * 4 + rr;
      const int sw  = (row & 7) << 4;
      char* rbase = Pb + row * 2048;
      const int p0 = (lane * 16) ^ sw;           // cols lane*8..+7
      half8 v0 = *(half8*)(rbase + p0);
      half8 v1 = *(half8*)(rbase + 1024 + p0);   // cols 512+lane*8..
      float f[16];
#pragma unroll
      for (int e = 0; e < 8; ++e) { f[e] = (float)v0[e]; f[e+8] = (float)v1[e]; }
      float mx = f[0];
#pragma unroll
      for (int e = 1; e < 16; ++e) mx = fmaxf(mx, f[e]);
      for (int d = 1; d < 64; d <<= 1) mx = fmaxf(mx, __shfl_xor(mx, d));
      float sum = 0.f;
#pragma unroll
      for (int e = 0; e < 16; ++e) { f[e] = exp2f((f[e] - mx) * ksc); sum += f[e]; }
      for (int d = 1; d < 64; d <<= 1) sum += __shfl_xor(sum, d);
      const float inv = 1.f / sum;
#pragma unroll
      for (int e = 0; e < 8; ++e) { v0[e] = (f16)(f[e]*inv); v1[e] = (f16)(f[e+8]*inv); }
      f16* dst = ptile + (size_t)row * C_ + lane * 8;
      *(half8*)dst         = v0;
      *(half8*)(dst + 512) = v1;
    }
  }
}

// ---------------------------------------------------------------------------
// Kernel B: y = P . V ; out = x + y. No LDS, no barriers; 256 thr, grid 2048.
// bi bits: [10:9]=b-hi [8:5]=rb [4:3]=quarter [2:0]=b-lo (XCD affinity on b).
// ---------------------------------------------------------------------------
__global__ __launch_bounds__(256, 4)
void chanattn_pv(const float* __restrict__ x, const f16* __restrict__ ws,
                 const f16* __restrict__ pws, float* __restrict__ out) {
  const int bi = blockIdx.x;
  const int b  = ((bi >> 9) << 3) | (bi & 7);
  const int rb = (bi >> 5) & 15;
  const int qd = (bi >> 3) & 3;
  const int q0 = rb * BQ;

  const int tid  = threadIdx.x;
  const int wl   = tid >> 6;    // 0..3
  const int lane = tid & 63;
  const int l15  = lane & 15;
  const int l4   = lane >> 4;

  const f16* mV = ws + MV_OFF + (size_t)b * MV_BATCH;
  const f16* pB = pws + (size_t)(b * 16 + rb) * P_TILE;

  for (int si = 0; si < 4; ++si) {
    const int s = qd + 4 * wl + 16 * si;       // strip 0..48, wave-uniform
    if (s >= 49) break;
    const int d = s * 16 + l15;
    const f16* vB = mV + (size_t)s * 32 * 512;
    f32x4 a2[4] = {};
    for (int t = 0; t < 16; ++t) {
      half8 afr[4];
#pragma unroll
      for (int rf = 0; rf < 4; ++rf)
        afr[rf] = *(const half8*)(pB + (size_t)(rf * 16 + l15) * C_ + t * 64 + l4 * 8);
      half8 afr2[4];
#pragma unroll
      for (int rf = 0; rf < 4; ++rf)
        afr2[rf] = *(const half8*)(pB + (size_t)(rf * 16 + l15) * C_ + t * 64 + 32 + l4 * 8);
      const half8 b0 = *(const half8*)(vB + (size_t)(t * 2    ) * 512 + lane * 8);
      const half8 b1 = *(const half8*)(vB + (size_t)(t * 2 + 1) * 512 + lane * 8);
#pragma unroll
      for (int rf = 0; rf < 4; ++rf)
        a2[rf] = __builtin_amdgcn_mfma_f32_16x16x32_f16(afr[rf], b0, a2[rf], 0, 0, 0);
#pragma unroll
      for (int rf = 0; rf < 4; ++rf)
        a2[rf] = __builtin_amdgcn_mfma_f32_16x16x32_f16(afr2[rf], b1, a2[rf], 0, 0, 0);
    }
#pragma unroll
    for (int rf = 0; rf < 4; ++rf)
#pragma unroll
      for (int r = 0; r < 4; ++r) {
        const size_t idx = (size_t)(b * C_ + q0 + rf * 16 + l4 * 4 + r) * HW_ + d;
        out[idx] = x[idx] + a2[rf][r];
      }
  }
}

// ---------------------------------------------------------------------------
// Monolithic r6 kernel (used when ws can't hold the P buffer). Verified 175us.
// ---------------------------------------------------------------------------
__global__ __launch_bounds__(1024, 4)
void chanattn_mono(const float* __restrict__ x, const f16* __restrict__ ws,
                   float* __restrict__ out) {
  __shared__ f16 Pl[BQ * C_];   // 128 KiB
  char* Pb = (char*)Pl;

  const int bi   = blockIdx.x;
  const int slot = bi >> 3;
  const int b    = ((slot >> 4) << 3) | (bi & 7);
  const int rb   = slot & 15;
  const int q0   = rb * BQ;

  const int tid  = threadIdx.x;
  const int w    = tid >> 6;
  const int lane = tid & 63;
  const int l15  = lane & 15;
  const int l4   = lane >> 4;

  const f16* mA = ws + (size_t)b * MA_BATCH;
  const f16* tA = ws + TA_OFF + (size_t)b * TA_BATCH;
  const f16* mV = ws + MV_OFF + (size_t)b * MV_BATCH;
  const int pa = q0 >> 4;

  {
    f32x4 acc[4][4] = {};
    for (int kc = 0; kc < 24; ++kc) {
      half8 afr[4], bfr[4];
#pragma unroll
      for (int rf = 0; rf < 4; ++rf)
        afr[rf] = *(const half8*)(mA + ((size_t)(pa + rf) * 24 + kc) * 512 + lane * 8);
#pragma unroll
      for (int cf = 0; cf < 4; ++cf)
        bfr[cf] = *(const half8*)(mA + ((size_t)(w * 4 + cf) * 24 + kc) * 512 + lane * 8);
#pragma unroll
      for (int rf = 0; rf < 4; ++rf)
#pragma unroll
        for (int cf = 0; cf < 4; ++cf)
          acc[rf][cf] = __builtin_amdgcn_mfma_f32_16x16x32_f16(afr[rf], bfr[cf], acc[rf][cf], 0, 0, 0);
    }
    {
      half8 afr[4], bfr[4];
#pragma unroll
      for (int rf = 0; rf < 4; ++rf) {
        half8 v = {};
        if (l4 < 2) v = *(const half8*)(tA + (pa + rf) * 256 + lane * 8);
        afr[rf] = v;
      }
#pragma unroll
      for (int cf = 0; cf < 4; ++cf) {
        half8 v = {};
        if (l4 < 2) v = *(const half8*)(tA + (w * 4 + cf) * 256 + lane * 8);
        bfr[cf] = v;
      }
#pragma unroll
      for (int rf = 0; rf < 4; ++rf)
#pragma unroll
        for (int cf = 0; cf < 4; ++cf)
          acc[rf][cf] = __builtin_amdgcn_mfma_f32_16x16x32_f16(afr[rf], bfr[cf], acc[rf][cf], 0, 0, 0);
    }
#pragma unroll
    for (int rf = 0; rf < 4; ++rf)
#pragma unroll
      for (int cf = 0; cf < 4; ++cf)
#pragma unroll
        for (int r = 0; r < 4; ++r) {
          const int row = rf * 16 + l4 * 4 + r;
          const int col = w * 64 + cf * 16 + l15;
          int byte = row * 2048 + col * 2;
          byte ^= (row & 7) << 4;
          *(f16*)(Pb + byte) = (f16)acc[rf][cf][r];
        }
  }
  __syncthreads();
  {
    const float ksc = 0.045084223f;
    for (int rr = 0; rr < 4; ++rr) {
      const int row = w * 4 + rr;
      const int sw  = (row & 7) << 4;
      char* rbase = Pb + row * 2048;
      const int p0 = (lane * 16) ^ sw;
      half8 v0 = *(half8*)(rbase + p0);
      half8 v1 = *(half8*)(rbase + 1024 + p0);
      float f[16];
#pragma unroll
      for (int e = 0; e < 8; ++e) { f[e] = (float)v0[e]; f[e+8] = (float)v1[e]; }
      float mx = f[0];
#pragma unroll
      for (int e = 1; e < 16; ++e) mx = fmaxf(mx, f[e]);
      for (int d = 1; d < 64; d <<= 1) mx = fmaxf(mx, __shfl_xor(mx, d));
      float sum = 0.f;
#pragma unroll
      for (int e = 0; e < 16; ++e) { f[e] = exp2f((f[e] - mx) * ksc); sum += f[e]; }
      for (int d = 1; d < 64; d <<= 1) sum += __shfl_xor(sum, d);
      const float inv = 1.f / sum;
#pragma unroll
      for (int e = 0; e < 8; ++e) { v0[e] = (f16)(f[e]*inv); v1[e] = (f16)(f[e+8]*inv); }
      *(half8*)(rbase + p0) = v0;
      *(half8*)(rbase + 1024 + p0) = v1;
    }
  }
  __syncthreads();
  {
    f32x4 a2[4][4] = {};
    for (int t = 0; t < 16; ++t) {
      half8 afr[4][2];
#pragma unroll
      for (int rf = 0; rf < 4; ++rf)
#pragma unroll
        for (int kf = 0; kf < 2; ++kf) {
          const int row = rf * 16 + l15;
          int byte = row * 2048 + t * 128 + kf * 64 + (l4 << 4);
          byte ^= (row & 7) << 4;
          afr[rf][kf] = *(half8*)(Pb + byte);
        }
#pragma unroll
      for (int si = 0; si < 4; ++si) {
        const int s = w + 16 * si;
        if (s < 49) {
#pragma unroll
          for (int kf = 0; kf < 2; ++kf) {
            const half8 bfr = *(const half8*)(mV + ((size_t)s * 32 + t * 2 + kf) * 512 + lane * 8);
#pragma unroll
            for (int rf = 0; rf < 4; ++rf)
              a2[si][rf] = __builtin_amdgcn_mfma_f32_16x16x32_f16(afr[rf][kf], bfr, a2[si][rf], 0, 0, 0);
          }
        }
      }
    }
#pragma unroll
    for (int si = 0; si < 4; ++si) {
      const int s = w + 16 * si;
      if (s < 49) {
        const int d = s * 16 + l15;
#pragma unroll
        for (int rf = 0; rf < 4; ++rf)
#pragma unroll
          for (int r = 0; r < 4; ++r) {
            const size_t idx = (size_t)(b * C_ + q0 + rf * 16 + l4 * 4 + r) * HW_ + d;
            out[idx] = x[idx] + a2[si][rf][r];
          }
      }
    }
  }
}

// ---------------------------------------------------------------------------
// Fallback (round-1 kernel): only if ws too small for everything.
// ---------------------------------------------------------------------------
__device__ __forceinline__ half8 pack8(const float4& a, const float4& b) {
  half8 r;
  r[0]=(f16)a.x; r[1]=(f16)a.y; r[2]=(f16)a.z; r[3]=(f16)a.w;
  r[4]=(f16)b.x; r[5]=(f16)b.y; r[6]=(f16)b.z; r[7]=(f16)b.w;
  return r;
}

__global__ __launch_bounds__(512, 2)
void chanattn_fallback(const float* __restrict__ x, float* __restrict__ out) {
  __shared__ f16 Pl[BQ * C_];
  const int bi   = blockIdx.x;
  const int slot = bi >> 3;
  const int b    = ((slot >> 4) << 3) | (bi & 7);
  const int rb   = slot & 15;
  const int q0   = rb * BQ;
  const int tid  = threadIdx.x;
  const int w    = tid >> 6;
  const int lane = tid & 63;
  const int l15  = lane & 15;
  const int l4   = lane >> 4;
  const float* mb = x + (size_t)b * (C_ * HW_);
  char* Pb = (char*)Pl;
  {
    const int cw = w * 128;
    for (int tile = 0; tile < 2; ++tile) {
      const int c0 = cw + tile * 64;
      f32x4 acc[4][4] = {};
      for (int kc = 0; kc < 25; ++kc) {
        const int k0 = kc * 32 + l4 * 8;
        const bool ok = (k0 < HW_);
        half8 afr[4], bfr[4];
#pragma unroll
        for (int rf = 0; rf < 4; ++rf) {
          if (ok) { const float4* p = (const float4*)(mb + (q0 + rf*16 + l15) * HW_ + k0); afr[rf] = pack8(p[0], p[1]); }
          else {
#pragma unroll
            for (int e = 0; e < 8; ++e) afr[rf][e] = (f16)0.f; }
        }
#pragma unroll
        for (int cf = 0; cf < 4; ++cf) {
          if (ok) { const float4* p = (const float4*)(mb + (c0 + cf*16 + l15) * HW_ + k0); bfr[cf] = pack8(p[0], p[1]); }
          else {
#pragma unroll
            for (int e = 0; e < 8; ++e) bfr[cf][e] = (f16)0.f; }
        }
#pragma unroll
        for (int rf = 0; rf < 4; ++rf)
#pragma unroll
          for (int cf = 0; cf < 4; ++cf)
            acc[rf][cf] = __builtin_amdgcn_mfma_f32_16x16x32_f16(afr[rf], bfr[cf], acc[rf][cf], 0, 0, 0);
      }
#pragma unroll
      for (int rf = 0; rf < 4; ++rf)
#pragma unroll
        for (int cf = 0; cf < 4; ++cf)
#pragma unroll
          for (int r = 0; r < 4; ++r) {
            const int row = rf*16 + l4*4 + r;
            const int col = c0 + cf*16 + l15;
            int byte = row*2048 + col*2;
            byte ^= (row & 7) << 4;
            *(f16*)(Pb + byte) = (f16)acc[rf][cf][r];
          }
    }
  }
  __syncthreads();
  {
    const float ksc = 0.045084223f;
    for (int rr = 0; rr < 8; ++rr) {
      const int row = w*8 + rr;
      const int sw  = (row & 7) << 4;
      char* rbase = Pb + row*2048;
      const int p0 = (lane * 16) ^ sw;
      half8 v0 = *(half8*)(rbase + p0);
      half8 v1 = *(half8*)(rbase + 1024 + p0);
      float f[16];
#pragma unroll
      for (int e = 0; e < 8; ++e) { f[e] = (float)v0[e]; f[e+8] = (float)v1[e]; }
      float mx = f[0];
#pragma unroll
      for (int e = 1; e < 16; ++e) mx = fmaxf(mx, f[e]);
      for (int d = 1; d < 64; d <<= 1) mx = fmaxf(mx, __shfl_xor(mx, d));
      float sum = 0.f;
#pragma unroll
      for (int e = 0; e < 16; ++e) { f[e] = exp2f((f[e] - mx) * ksc); sum += f[e]; }
      for (int d = 1; d < 64; d <<= 1) sum += __shfl_xor(sum, d);
      const float inv = 1.f / sum;
#pragma unroll
      for (int e = 0; e < 8; ++e) { v0[e] = (f16)(f[e]*inv); v1[e] = (f16)(f[e+8]*inv); }
      *(half8*)(rbase + p0) = v0;
      *(half8*)(rbase + 1024 + p0) = v1;
    }
  }
  __syncthreads();
  {
    f32x4 acc[7][4] = {};
    for (int t = 0; t < 16; ++t) {
      half8 afr[4][2];
#pragma unroll
      for (int rf = 0; rf < 4; ++rf)
#pragma unroll
        for (int kf = 0; kf < 2; ++kf) {
          const int row = rf*16 + l15;
          int byte = row*2048 + t*128 + kf*64 + l4*16;
          byte ^= (row & 7) << 4;
          afr[rf][kf] = *(half8*)(Pb + byte);
        }
#pragma unroll
      for (int si = 0; si < 7; ++si) {
        const int s = w + 8*si;
        if (s < 49) {
          const int d = s*16 + l15;
#pragma unroll
          for (int kf = 0; kf < 2; ++kf) {
            const int kv = t*64 + kf*32 + l4*8;
            half8 bfr;
#pragma unroll
            for (int e = 0; e < 8; ++e) bfr[e] = (f16)mb[(kv + e) * HW_ + d];
#pragma unroll
            for (int rf = 0; rf < 4; ++rf)
              acc[si][rf] = __builtin_amdgcn_mfma_f32_16x16x32_f16(afr[rf][kf], bfr, acc[si][rf], 0, 0, 0);
          }
        }
      }
    }
#pragma unroll
    for (int si = 0; si < 7; ++si) {
      const int s = w + 8*si;
      if (s < 49) {
        const int d = s*16 + l15;
#pragma unroll
        for (int rf = 0; rf < 4; ++rf)
#pragma unroll
          for (int r = 0; r < 4; ++r) {
            const size_t idx = (size_t)(b*C_ + q0 + rf*16 + l4*4 + r) * HW_ + d;
            out[idx] = x[idx] + acc[si][rf][r];
          }
      }
    }
  }
}

extern "C" void kernel_launch(void* const* d_in, const int* in_sizes, int n_in,
                              void* d_out, int out_size, void* d_ws, size_t ws_size,
                              hipStream_t stream) {
  const float* x = (const float*)d_in[0];
  float* out = (float*)d_out;
  const size_t need1 = P_OFF * 2;                          // 102,760,448 B
  const size_t need2 = (P_OFF + 512ull * P_TILE) * 2;      // 169,869,312 B
  if (ws_size >= need2) {
    f16* ws  = (f16*)d_ws;
    f16* pws = ws + P_OFF;
    prep_kernel<<<dim3(32 * 16 * 13), dim3(256), 0, stream>>>(x, ws);
    chanattn_qk<<<dim3(512), dim3(1024), 0, stream>>>(ws, pws);
    chanattn_pv<<<dim3(2048), dim3(256), 0, stream>>>(x, ws, pws, out);
  } else if (ws_size >= need1) {
    f16* ws = (f16*)d_ws;
    prep_kernel<<<dim3(32 * 16 * 13), dim3(256), 0, stream>>>(x, ws);
    chanattn_mono<<<dim3(512), dim3(1024), 0, stream>>>(x, ws, out);
  } else {
    chanattn_fallback<<<dim3(512), dim3(512), 0, stream>>>(x, out);
  }
}

// Round 12
// 262.444 us; speedup vs baseline: 2.1233x; 2.1233x over previous
//
#include <hip/hip_runtime.h>

typedef _Float16 f16;
typedef f16  half8 __attribute__((ext_vector_type(8)));
typedef float f32x4 __attribute__((ext_vector_type(4)));

#define B_   32
#define C_   1024
#define HW_  784
#define BQ   64

// Fragment-packed workspace layouts (offsets in f16 elements):
//  mA   [b][panel=c>>4][kc=0..23][lane]  half8 along k=kc*32+(lane>>4)*8, row c=panel*16+(lane&15)
//  tailA[b][panel][sl=0..1][l15]         half8 along k=768+sl*8 (valid lanes l4<2)
//  mV   [b][pd=d>>4 (49)][kt=kv>>5][lane] half8 along kv=kt*32+(lane>>4)*8, row d=pd*16+(lane&15)
//  P    [tile=b*16+rb][frag=pr*32+kc][lane*8]  A-fragment-packed softmaxed P
//        (frag: row=pr*16+(lane&15), k=kc*32+(lane>>4)*8)
#define MA_BATCH  786432ull        // 64*24*512
#define TA_OFF    25165824ull      // 32*MA_BATCH
#define TA_BATCH  16384ull         // 64*2*16*8
#define MV_OFF    25690112ull      // TA_OFF + 32*TA_BATCH
#define MV_BATCH  802816ull        // 49*32*512
#define P_OFF     51380224ull      // MV_OFF + 32*MV_BATCH  (== 102,760,448 bytes)
#define P_TILE    65536ull         // 128 frags * 512 f16 per tile
// split ws = (P_OFF + 512*P_TILE)*2 = 169,869,312 bytes (proven available r11)

// ---------------------------------------------------------------------------
// Prep: build mA / tailA / mV from x (f32 -> f16, fragment-packed). (r6)
// ---------------------------------------------------------------------------
__global__ __launch_bounds__(256)
void prep_kernel(const float* __restrict__ x, f16* __restrict__ ws) {
  __shared__ f16 lt[64][72];
  const int bi = blockIdx.x;               // b*208 + ct*13 + ht
  const int ht = bi % 13;
  const int ct = (bi / 13) & 15;
  const int b  = bi / 208;
  const int h0 = ht * 64, c0 = ct * 64;
  const int t = threadIdx.x, r = t >> 2, q = t & 3;

  f16* mA = ws + (size_t)b * MA_BATCH;
  f16* tA = ws + TA_OFF + (size_t)b * TA_BATCH;
  f16* mV = ws + MV_OFF + (size_t)b * MV_BATCH;

  const int c  = c0 + r;
  const int pc = c >> 4, cl = c & 15;
  const int hq = h0 + q * 16;
  if (hq < HW_) {
    const float* src = x + (size_t)b * (C_ * HW_) + (size_t)c * HW_ + hq;
    float f[16];
#pragma unroll
    for (int j = 0; j < 4; ++j) ((float4*)f)[j] = ((const float4*)src)[j];
    f16 h[16];
#pragma unroll
    for (int j = 0; j < 16; ++j) h[j] = (f16)f[j];
    if (hq < 768) {
      const int kc = hq >> 5;
      const int l4 = (hq >> 3) & 3;          // 0 or 2
      f16* d0 = mA + ((size_t)pc * 24 + kc) * 512 + ((l4    ) * 16 + cl) * 8;
      f16* d1 = mA + ((size_t)pc * 24 + kc) * 512 + ((l4 + 1) * 16 + cl) * 8;
      *(half8*)d0 = *(half8*)h;
      *(half8*)d1 = *(half8*)(h + 8);
    } else {                                  // hq == 768: tail chunk
      f16* d0 = tA + pc * 256 + cl * 8;
      f16* d1 = tA + pc * 256 + 128 + cl * 8;
      *(half8*)d0 = *(half8*)h;
      *(half8*)d1 = *(half8*)(h + 8);
    }
    *(half8*)&lt[r][q * 16]     = *(half8*)h;
    *(half8*)&lt[r][q * 16 + 8] = *(half8*)(h + 8);
  }
  __syncthreads();
  // transposed side -> mV (d = hw, kv = c)
  if (h0 + r < HW_) {
    f16 g[16];
#pragma unroll
    for (int j = 0; j < 16; ++j) g[j] = lt[q * 16 + j][r];
    const int d  = h0 + r;
    const int pd = d >> 4, dl = d & 15;
    const int kv = c0 + q * 16;
    const int kt = kv >> 5;
    const int l4 = (kv >> 3) & 3;            // 0 or 2
    f16* e0 = mV + ((size_t)pd * 32 + kt) * 512 + ((l4    ) * 16 + dl) * 8;
    f16* e1 = mV + ((size_t)pd * 32 + kt) * 512 + ((l4 + 1) * 16 + dl) * 8;
    *(half8*)e0 = *(half8*)g;
    *(half8*)e1 = *(half8*)(g + 8);
  }
}

// ---------------------------------------------------------------------------
// Kernel A: phase 1 + softmax (back to LDS) + fragment-pack P -> ws.
// ---------------------------------------------------------------------------
__global__ __launch_bounds__(1024, 4)
void chanattn_qk(const f16* __restrict__ ws, f16* __restrict__ pws) {
  __shared__ f16 Pl[BQ * C_];   // 128 KiB
  char* Pb = (char*)Pl;

  const int bi   = blockIdx.x;
  const int slot = bi >> 3;
  const int b    = ((slot >> 4) << 3) | (bi & 7);   // same-batch WGs share an XCD
  const int rb   = slot & 15;
  const int q0   = rb * BQ;

  const int tid  = threadIdx.x;
  const int w    = tid >> 6;
  const int lane = tid & 63;
  const int l15  = lane & 15;
  const int l4   = lane >> 4;

  const f16* mA = ws + (size_t)b * MA_BATCH;
  const f16* tA = ws + TA_OFF + (size_t)b * TA_BATCH;
  const int pa = q0 >> 4;

  // ---------------- Phase 1 (r6) ----------------
  {
    f32x4 acc[4][4] = {};
    for (int kc = 0; kc < 24; ++kc) {
      half8 afr[4], bfr[4];
#pragma unroll
      for (int rf = 0; rf < 4; ++rf)
        afr[rf] = *(const half8*)(mA + ((size_t)(pa + rf) * 24 + kc) * 512 + lane * 8);
#pragma unroll
      for (int cf = 0; cf < 4; ++cf)
        bfr[cf] = *(const half8*)(mA + ((size_t)(w * 4 + cf) * 24 + kc) * 512 + lane * 8);
#pragma unroll
      for (int rf = 0; rf < 4; ++rf)
#pragma unroll
        for (int cf = 0; cf < 4; ++cf)
          acc[rf][cf] = __builtin_amdgcn_mfma_f32_16x16x32_f16(afr[rf], bfr[cf], acc[rf][cf], 0, 0, 0);
    }
    { // tail chunk k=768..783 (zero for l4>=2)
      half8 afr[4], bfr[4];
#pragma unroll
      for (int rf = 0; rf < 4; ++rf) {
        half8 v = {};
        if (l4 < 2) v = *(const half8*)(tA + (pa + rf) * 256 + lane * 8);
        afr[rf] = v;
      }
#pragma unroll
      for (int cf = 0; cf < 4; ++cf) {
        half8 v = {};
        if (l4 < 2) v = *(const half8*)(tA + (w * 4 + cf) * 256 + lane * 8);
        bfr[cf] = v;
      }
#pragma unroll
      for (int rf = 0; rf < 4; ++rf)
#pragma unroll
        for (int cf = 0; cf < 4; ++cf)
          acc[rf][cf] = __builtin_amdgcn_mfma_f32_16x16x32_f16(afr[rf], bfr[cf], acc[rf][cf], 0, 0, 0);
    }
    // raw scores -> LDS (XOR swizzle)
#pragma unroll
    for (int rf = 0; rf < 4; ++rf)
#pragma unroll
      for (int cf = 0; cf < 4; ++cf)
#pragma unroll
        for (int r = 0; r < 4; ++r) {
          const int row = rf * 16 + l4 * 4 + r;
          const int col = w * 64 + cf * 16 + l15;
          int byte = row * 2048 + col * 2;
          byte ^= (row & 7) << 4;
          *(f16*)(Pb + byte) = (f16)acc[rf][cf][r];
        }
  }
  __syncthreads();

  // ---------------- softmax rows w*4..w*4+3, normalized back to LDS ----------------
  {
    const float ksc = 0.045084223f;   // log2(e)/32
    for (int rr = 0; rr < 4; ++rr) {
      const int row = w * 4 + rr;
      const int sw  = (row & 7) << 4;
      char* rbase = Pb + row * 2048;
      const int p0 = (lane * 16) ^ sw;
      half8 v0 = *(half8*)(rbase + p0);
      half8 v1 = *(half8*)(rbase + 1024 + p0);
      float f[16];
#pragma unroll
      for (int e = 0; e < 8; ++e) { f[e] = (float)v0[e]; f[e+8] = (float)v1[e]; }
      float mx = f[0];
#pragma unroll
      for (int e = 1; e < 16; ++e) mx = fmaxf(mx, f[e]);
      for (int d = 1; d < 64; d <<= 1) mx = fmaxf(mx, __shfl_xor(mx, d));
      float sum = 0.f;
#pragma unroll
      for (int e = 0; e < 16; ++e) { f[e] = exp2f((f[e] - mx) * ksc); sum += f[e]; }
      for (int d = 1; d < 64; d <<= 1) sum += __shfl_xor(sum, d);
      const float inv = 1.f / sum;
#pragma unroll
      for (int e = 0; e < 8; ++e) { v0[e] = (f16)(f[e]*inv); v1[e] = (f16)(f[e+8]*inv); }
      *(half8*)(rbase + p0) = v0;
      *(half8*)(rbase + 1024 + p0) = v1;
    }
  }
  __syncthreads();

  // ---------------- pack pass: LDS -> ws, A-fragment layout (coalesced) ----------------
  {
    f16* ptile = pws + (size_t)(b * 16 + rb) * P_TILE;
#pragma unroll
    for (int j = 0; j < 8; ++j) {
      const int f  = w * 8 + j;           // 0..127
      const int pr = f >> 5, kc = f & 31;
      const int row = pr * 16 + l15;
      int byte = row * 2048 + kc * 64 + l4 * 16;
      byte ^= (row & 7) << 4;
      const half8 v = *(half8*)(Pb + byte);
      *(half8*)(ptile + (size_t)f * 512 + lane * 8) = v;
    }
  }
}

// ---------------------------------------------------------------------------
// Kernel B: y = P . V ; out = x + y.  Mono phase-2 structure, P from ws
// (fragment-packed, fully coalesced). 256 thr, no LDS, no barriers.
// bi bits: [10:9]=b-hi [8:5]=rb [4:3]=quarter [2:0]=b-lo (XCD affinity on b).
// ---------------------------------------------------------------------------
__global__ __launch_bounds__(256, 4)
void chanattn_pv(const float* __restrict__ x, const f16* __restrict__ ws,
                 const f16* __restrict__ pws, float* __restrict__ out) {
  const int bi = blockIdx.x;
  const int b  = ((bi >> 9) << 3) | (bi & 7);
  const int rb = (bi >> 5) & 15;
  const int qd = (bi >> 3) & 3;
  const int q0 = rb * BQ;

  const int tid  = threadIdx.x;
  const int wl   = tid >> 6;    // 0..3
  const int lane = tid & 63;
  const int l15  = lane & 15;
  const int l4   = lane >> 4;

  const f16* mV = ws + MV_OFF + (size_t)b * MV_BATCH;
  const f16* pB = pws + (size_t)(b * 16 + rb) * P_TILE;

  f32x4 a2[4][4] = {};   // [si][rf]
  for (int t = 0; t < 16; ++t) {
    half8 afr[4][2];
#pragma unroll
    for (int pr = 0; pr < 4; ++pr)
#pragma unroll
      for (int kf = 0; kf < 2; ++kf)
        afr[pr][kf] = *(const half8*)(pB + (size_t)(pr * 32 + t * 2 + kf) * 512 + lane * 8);
#pragma unroll
    for (int si = 0; si < 4; ++si) {
      const int s = qd + 4 * wl + 16 * si;
      if (s < 49) {                              // wave-uniform
#pragma unroll
        for (int kf = 0; kf < 2; ++kf) {
          const half8 bfr = *(const half8*)(mV + ((size_t)s * 32 + t * 2 + kf) * 512 + lane * 8);
#pragma unroll
          for (int rf = 0; rf < 4; ++rf)
            a2[si][rf] = __builtin_amdgcn_mfma_f32_16x16x32_f16(afr[rf][kf], bfr, a2[si][rf], 0, 0, 0);
        }
      }
    }
  }
#pragma unroll
  for (int si = 0; si < 4; ++si) {
    const int s = qd + 4 * wl + 16 * si;
    if (s < 49) {
      const int d = s * 16 + l15;
#pragma unroll
      for (int rf = 0; rf < 4; ++rf)
#pragma unroll
        for (int r = 0; r < 4; ++r) {
          const size_t idx = (size_t)(b * C_ + q0 + rf * 16 + l4 * 4 + r) * HW_ + d;
          out[idx] = x[idx] + a2[si][rf][r];
        }
    }
  }
}

// ---------------------------------------------------------------------------
// Monolithic r6 kernel (ws can't hold P). Verified 175us main.
// ---------------------------------------------------------------------------
__global__ __launch_bounds__(1024, 4)
void chanattn_mono(const float* __restrict__ x, const f16* __restrict__ ws,
                   float* __restrict__ out) {
  __shared__ f16 Pl[BQ * C_];
  char* Pb = (char*)Pl;

  const int bi   = blockIdx.x;
  const int slot = bi >> 3;
  const int b    = ((slot >> 4) << 3) | (bi & 7);
  const int rb   = slot & 15;
  const int q0   = rb * BQ;

  const int tid  = threadIdx.x;
  const int w    = tid >> 6;
  const int lane = tid & 63;
  const int l15  = lane & 15;
  const int l4   = lane >> 4;

  const f16* mA = ws + (size_t)b * MA_BATCH;
  const f16* tA = ws + TA_OFF + (size_t)b * TA_BATCH;
  const f16* mV = ws + MV_OFF + (size_t)b * MV_BATCH;
  const int pa = q0 >> 4;

  {
    f32x4 acc[4][4] = {};
    for (int kc = 0; kc < 24; ++kc) {
      half8 afr[4], bfr[4];
#pragma unroll
      for (int rf = 0; rf < 4; ++rf)
        afr[rf] = *(const half8*)(mA + ((size_t)(pa + rf) * 24 + kc) * 512 + lane * 8);
#pragma unroll
      for (int cf = 0; cf < 4; ++cf)
        bfr[cf] = *(const half8*)(mA + ((size_t)(w * 4 + cf) * 24 + kc) * 512 + lane * 8);
#pragma unroll
      for (int rf = 0; rf < 4; ++rf)
#pragma unroll
        for (int cf = 0; cf < 4; ++cf)
          acc[rf][cf] = __builtin_amdgcn_mfma_f32_16x16x32_f16(afr[rf], bfr[cf], acc[rf][cf], 0, 0, 0);
    }
    {
      half8 afr[4], bfr[4];
#pragma unroll
      for (int rf = 0; rf < 4; ++rf) {
        half8 v = {};
        if (l4 < 2) v = *(const half8*)(tA + (pa + rf) * 256 + lane * 8);
        afr[rf] = v;
      }
#pragma unroll
      for (int cf = 0; cf < 4; ++cf) {
        half8 v = {};
        if (l4 < 2) v = *(const half8*)(tA + (w * 4 + cf) * 256 + lane * 8);
        bfr[cf] = v;
      }
#pragma unroll
      for (int rf = 0; rf < 4; ++rf)
#pragma unroll
        for (int cf = 0; cf < 4; ++cf)
          acc[rf][cf] = __builtin_amdgcn_mfma_f32_16x16x32_f16(afr[rf], bfr[cf], acc[rf][cf], 0, 0, 0);
    }
#pragma unroll
    for (int rf = 0; rf < 4; ++rf)
#pragma unroll
      for (int cf = 0; cf < 4; ++cf)
#pragma unroll
        for (int r = 0; r < 4; ++r) {
          const int row = rf * 16 + l4 * 4 + r;
          const int col = w * 64 + cf * 16 + l15;
          int byte = row * 2048 + col * 2;
          byte ^= (row & 7) << 4;
          *(f16*)(Pb + byte) = (f16)acc[rf][cf][r];
        }
  }
  __syncthreads();
  {
    const float ksc = 0.045084223f;
    for (int rr = 0; rr < 4; ++rr) {
      const int row = w * 4 + rr;
      const int sw  = (row & 7) << 4;
      char* rbase = Pb + row * 2048;
      const int p0 = (lane * 16) ^ sw;
      half8 v0 = *(half8*)(rbase + p0);
      half8 v1 = *(half8*)(rbase + 1024 + p0);
      float f[16];
#pragma unroll
      for (int e = 0; e < 8; ++e) { f[e] = (float)v0[e]; f[e+8] = (float)v1[e]; }
      float mx = f[0];
#pragma unroll
      for (int e = 1; e < 16; ++e) mx = fmaxf(mx, f[e]);
      for (int d = 1; d < 64; d <<= 1) mx = fmaxf(mx, __shfl_xor(mx, d));
      float sum = 0.f;
#pragma unroll
      for (int e = 0; e < 16; ++e) { f[e] = exp2f((f[e] - mx) * ksc); sum += f[e]; }
      for (int d = 1; d < 64; d <<= 1) sum += __shfl_xor(sum, d);
      const float inv = 1.f / sum;
#pragma unroll
      for (int e = 0; e < 8; ++e) { v0[e] = (f16)(f[e]*inv); v1[e] = (f16)(f[e+8]*inv); }
      *(half8*)(rbase + p0) = v0;
      *(half8*)(rbase + 1024 + p0) = v1;
    }
  }
  __syncthreads();
  {
    f32x4 a2[4][4] = {};
    for (int t = 0; t < 16; ++t) {
      half8 afr[4][2];
#pragma unroll
      for (int rf = 0; rf < 4; ++rf)
#pragma unroll
        for (int kf = 0; kf < 2; ++kf) {
          const int row = rf * 16 + l15;
          int byte = row * 2048 + t * 128 + kf * 64 + (l4 << 4);
          byte ^= (row & 7) << 4;
          afr[rf][kf] = *(half8*)(Pb + byte);
        }
#pragma unroll
      for (int si = 0; si < 4; ++si) {
        const int s = w + 16 * si;
        if (s < 49) {
#pragma unroll
          for (int kf = 0; kf < 2; ++kf) {
            const half8 bfr = *(const half8*)(mV + ((size_t)s * 32 + t * 2 + kf) * 512 + lane * 8);
#pragma unroll
            for (int rf = 0; rf < 4; ++rf)
              a2[si][rf] = __builtin_amdgcn_mfma_f32_16x16x32_f16(afr[rf][kf], bfr, a2[si][rf], 0, 0, 0);
          }
        }
      }
    }
#pragma unroll
    for (int si = 0; si < 4; ++si) {
      const int s = w + 16 * si;
      if (s < 49) {
        const int d = s * 16 + l15;
#pragma unroll
        for (int rf = 0; rf < 4; ++rf)
#pragma unroll
          for (int r = 0; r < 4; ++r) {
            const size_t idx = (size_t)(b * C_ + q0 + rf * 16 + l4 * 4 + r) * HW_ + d;
            out[idx] = x[idx] + a2[si][rf][r];
          }
      }
    }
  }
}

// ---------------------------------------------------------------------------
// Fallback (round-1 kernel): only if ws too small for everything.
// ---------------------------------------------------------------------------
__device__ __forceinline__ half8 pack8(const float4& a, const float4& b) {
  half8 r;
  r[0]=(f16)a.x; r[1]=(f16)a.y; r[2]=(f16)a.z; r[3]=(f16)a.w;
  r[4]=(f16)b.x; r[5]=(f16)b.y; r[6]=(f16)b.z; r[7]=(f16)b.w;
  return r;
}

__global__ __launch_bounds__(512, 2)
void chanattn_fallback(const float* __restrict__ x, float* __restrict__ out) {
  __shared__ f16 Pl[BQ * C_];
  const int bi   = blockIdx.x;
  const int slot = bi >> 3;
  const int b    = ((slot >> 4) << 3) | (bi & 7);
  const int rb   = slot & 15;
  const int q0   = rb * BQ;
  const int tid  = threadIdx.x;
  const int w    = tid >> 6;
  const int lane = tid & 63;
  const int l15  = lane & 15;
  const int l4   = lane >> 4;
  const float* mb = x + (size_t)b * (C_ * HW_);
  char* Pb = (char*)Pl;
  {
    const int cw = w * 128;
    for (int tile = 0; tile < 2; ++tile) {
      const int c0 = cw + tile * 64;
      f32x4 acc[4][4] = {};
      for (int kc = 0; kc < 25; ++kc) {
        const int k0 = kc * 32 + l4 * 8;
        const bool ok = (k0 < HW_);
        half8 afr[4], bfr[4];
#pragma unroll
        for (int rf = 0; rf < 4; ++rf) {
          if (ok) { const float4* p = (const float4*)(mb + (q0 + rf*16 + l15) * HW_ + k0); afr[rf] = pack8(p[0], p[1]); }
          else {
#pragma unroll
            for (int e = 0; e < 8; ++e) afr[rf][e] = (f16)0.f; }
        }
#pragma unroll
        for (int cf = 0; cf < 4; ++cf) {
          if (ok) { const float4* p = (const float4*)(mb + (c0 + cf*16 + l15) * HW_ + k0); bfr[cf] = pack8(p[0], p[1]); }
          else {
#pragma unroll
            for (int e = 0; e < 8; ++e) bfr[cf][e] = (f16)0.f; }
        }
#pragma unroll
        for (int rf = 0; rf < 4; ++rf)
#pragma unroll
          for (int cf = 0; cf < 4; ++cf)
            acc[rf][cf] = __builtin_amdgcn_mfma_f32_16x16x32_f16(afr[rf], bfr[cf], acc[rf][cf], 0, 0, 0);
      }
#pragma unroll
      for (int rf = 0; rf < 4; ++rf)
#pragma unroll
        for (int cf = 0; cf < 4; ++cf)
#pragma unroll
          for (int r = 0; r < 4; ++r) {
            const int row = rf*16 + l4*4 + r;
            const int col = c0 + cf*16 + l15;
            int byte = row*2048 + col*2;
            byte ^= (row & 7) << 4;
            *(f16*)(Pb + byte) = (f16)acc[rf][cf][r];
          }
    }
  }
  __syncthreads();
  {
    const float ksc = 0.045084223f;
    for (int rr = 0; rr < 8; ++rr) {
      const int row = w*8 + rr;
      const int sw  = (row & 7) << 4;
      char* rbase = Pb + row*2048;
      const int p0 = (lane * 16) ^ sw;
      half8 v0 = *(half8*)(rbase + p0);
      half8 v1 = *(half8*)(rbase + 1024 + p0);
      float f[16];
#pragma unroll
      for (int e = 0; e < 8; ++e) { f[e] = (float)v0[e]; f[e+8] = (float)v1[e]; }
      float mx = f[0];
#pragma unroll
      for (int e = 1; e < 16; ++e) mx = fmaxf(mx, f[e]);
      for (int d = 1; d < 64; d <<= 1) mx = fmaxf(mx, __shfl_xor(mx, d));
      float sum = 0.f;
#pragma unroll
      for (int e = 0; e < 16; ++e) { f[e] = exp2f((f[e] - mx) * ksc); sum += f[e]; }
      for (int d = 1; d < 64; d <<= 1) sum += __shfl_xor(sum, d);
      const float inv = 1.f / sum;
#pragma unroll
      for (int e = 0; e < 8; ++e) { v0[e] = (f16)(f[e]*inv); v1[e] = (f16)(f[e+8]*inv); }
      *(half8*)(rbase + p0) = v0;
      *(half8*)(rbase + 1024 + p0) = v1;
    }
  }
  __syncthreads();
  {
    f32x4 acc[7][4] = {};
    for (int t = 0; t < 16; ++t) {
      half8 afr[4][2];
#pragma unroll
      for (int rf = 0; rf < 4; ++rf)
#pragma unroll
        for (int kf = 0; kf < 2; ++kf) {
          const int row = rf*16 + l15;
          int byte = row*2048 + t*128 + kf*64 + l4*16;
          byte ^= (row & 7) << 4;
          afr[rf][kf] = *(half8*)(Pb + byte);
        }
#pragma unroll
      for (int si = 0; si < 7; ++si) {
        const int s = w + 8*si;
        if (s < 49) {
          const int d = s*16 + l15;
#pragma unroll
          for (int kf = 0; kf < 2; ++kf) {
            const int kv = t*64 + kf*32 + l4*8;
            half8 bfr;
#pragma unroll
            for (int e = 0; e < 8; ++e) bfr[e] = (f16)mb[(kv + e) * HW_ + d];
#pragma unroll
            for (int rf = 0; rf < 4; ++rf)
              acc[si][rf] = __builtin_amdgcn_mfma_f32_16x16x32_f16(afr[rf][kf], bfr, acc[si][rf], 0, 0, 0);
          }
        }
      }
    }
#pragma unroll
    for (int si = 0; si < 7; ++si) {
      const int s = w + 8*si;
      if (s < 49) {
        const int d = s*16 + l15;
#pragma unroll
        for (int rf = 0; rf < 4; ++rf)
#pragma unroll
          for (int r = 0; r < 4; ++r) {
            const size_t idx = (size_t)(b*C_ + q0 + rf*16 + l4*4 + r) * HW_ + d;
            out[idx] = x[idx] + acc[si][rf][r];
          }
      }
    }
  }
}

extern "C" void kernel_launch(void* const* d_in, const int* in_sizes, int n_in,
                              void* d_out, int out_size, void* d_ws, size_t ws_size,
                              hipStream_t stream) {
  const float* x = (const float*)d_in[0];
  float* out = (float*)d_out;
  const size_t need1 = P_OFF * 2;                          // 102,760,448 B
  const size_t need2 = (P_OFF + 512ull * P_TILE) * 2;      // 169,869,312 B
  if (ws_size >= need2) {
    f16* ws  = (f16*)d_ws;
    f16* pws = ws + P_OFF;
    prep_kernel<<<dim3(32 * 16 * 13), dim3(256), 0, stream>>>(x, ws);
    chanattn_qk<<<dim3(512), dim3(1024), 0, stream>>>(ws, pws);
    chanattn_pv<<<dim3(2048), dim3(256), 0, stream>>>(x, ws, pws, out);
  } else if (ws_size >= need1) {
    f16* ws = (f16*)d_ws;
    prep_kernel<<<dim3(32 * 16 * 13), dim3(256), 0, stream>>>(x, ws);
    chanattn_mono<<<dim3(512), dim3(1024), 0, stream>>>(x, ws, out);
  } else {
    chanattn_fallback<<<dim3(512), dim3(512), 0, stream>>>(x, out);
  }
}

// Round 13
// 220.187 us; speedup vs baseline: 2.5309x; 1.1919x over previous
//
#include <hip/hip_runtime.h>

typedef _Float16 f16;
typedef f16  half8 __attribute__((ext_vector_type(8)));
typedef float f32x4 __attribute__((ext_vector_type(4)));

#define B_   32
#define C_   1024
#define HW_  784

// Fragment-packed workspace layouts (offsets in f16 elements):
//  mA   [b][panel=c>>4][kc=0..23][lane]  half8 along k=kc*32+(lane>>4)*8, row c=panel*16+(lane&15)
//  tailA[b][panel][sl=0..1][l15]         half8 along k=768+sl*8 (valid lanes l4<2)
//  mV   [b][pd=d>>4 (49)][kt=kv>>5][lane] half8 along kv=kt*32+(lane>>4)*8, row d=pd*16+(lane&15)
#define MA_BATCH  786432ull        // 64*24*512
#define TA_OFF    25165824ull      // 32*MA_BATCH
#define TA_BATCH  16384ull         // 64*2*16*8
#define MV_OFF    25690112ull      // TA_OFF + 32*TA_BATCH
#define MV_BATCH  802816ull        // 49*32*512
#define WS_NEED   102760448ull     // (MV_OFF + 32*MV_BATCH)*2 bytes

// ---------------------------------------------------------------------------
// Prep: build mA / tailA / mV from x (f32 -> f16, fragment-packed). (r6)
// ---------------------------------------------------------------------------
__global__ __launch_bounds__(256)
void prep_kernel(const float* __restrict__ x, f16* __restrict__ ws) {
  __shared__ f16 lt[64][72];
  const int bi = blockIdx.x;               // b*208 + ct*13 + ht
  const int ht = bi % 13;
  const int ct = (bi / 13) & 15;
  const int b  = bi / 208;
  const int h0 = ht * 64, c0 = ct * 64;
  const int t = threadIdx.x, r = t >> 2, q = t & 3;

  f16* mA = ws + (size_t)b * MA_BATCH;
  f16* tA = ws + TA_OFF + (size_t)b * TA_BATCH;
  f16* mV = ws + MV_OFF + (size_t)b * MV_BATCH;

  const int c  = c0 + r;
  const int pc = c >> 4, cl = c & 15;
  const int hq = h0 + q * 16;
  if (hq < HW_) {
    const float* src = x + (size_t)b * (C_ * HW_) + (size_t)c * HW_ + hq;
    float f[16];
#pragma unroll
    for (int j = 0; j < 4; ++j) ((float4*)f)[j] = ((const float4*)src)[j];
    f16 h[16];
#pragma unroll
    for (int j = 0; j < 16; ++j) h[j] = (f16)f[j];
    if (hq < 768) {
      const int kc = hq >> 5;
      const int l4 = (hq >> 3) & 3;          // 0 or 2
      f16* d0 = mA + ((size_t)pc * 24 + kc) * 512 + ((l4    ) * 16 + cl) * 8;
      f16* d1 = mA + ((size_t)pc * 24 + kc) * 512 + ((l4 + 1) * 16 + cl) * 8;
      *(half8*)d0 = *(half8*)h;
      *(half8*)d1 = *(half8*)(h + 8);
    } else {                                  // hq == 768: tail chunk
      f16* d0 = tA + pc * 256 + cl * 8;
      f16* d1 = tA + pc * 256 + 128 + cl * 8;
      *(half8*)d0 = *(half8*)h;
      *(half8*)d1 = *(half8*)(h + 8);
    }
    *(half8*)&lt[r][q * 16]     = *(half8*)h;
    *(half8*)&lt[r][q * 16 + 8] = *(half8*)(h + 8);
  }
  __syncthreads();
  // transposed side -> mV (d = hw, kv = c)
  if (h0 + r < HW_) {
    f16 g[16];
#pragma unroll
    for (int j = 0; j < 16; ++j) g[j] = lt[q * 16 + j][r];
    const int d  = h0 + r;
    const int pd = d >> 4, dl = d & 15;
    const int kv = c0 + q * 16;
    const int kt = kv >> 5;
    const int l4 = (kv >> 3) & 3;            // 0 or 2
    f16* e0 = mV + ((size_t)pd * 32 + kt) * 512 + ((l4    ) * 16 + dl) * 8;
    f16* e1 = mV + ((size_t)pd * 32 + kt) * 512 + ((l4 + 1) * 16 + dl) * 8;
    *(half8*)e0 = *(half8*)g;
    *(half8*)e1 = *(half8*)(g + 8);
  }
}

// ---------------------------------------------------------------------------
// Main: BQ=32, 512 thr (8 waves), 64 KiB LDS -> 2 WGs/CU (desync overlap).
// Same per-wave register shape as r6 (no explicit prefetch -> no spill).
// ---------------------------------------------------------------------------
__global__ __launch_bounds__(512, 4)
void chanattn_main32(const float* __restrict__ x, const f16* __restrict__ ws,
                     float* __restrict__ out) {
  __shared__ f16 Pl[32 * C_];   // 64 KiB
  char* Pb = (char*)Pl;

  // grid 1024 = 32 batches x 32 row-blocks; same-batch WGs share an XCD
  const int bi = blockIdx.x;
  const int b  = ((bi >> 8) << 3) | (bi & 7);
  const int rb = (bi >> 3) & 31;
  const int q0 = rb * 32;

  const int tid  = threadIdx.x;
  const int w    = tid >> 6;    // 0..7
  const int lane = tid & 63;
  const int l15  = lane & 15;
  const int l4   = lane >> 4;

  const f16* mA = ws + (size_t)b * MA_BATCH;
  const f16* tA = ws + TA_OFF + (size_t)b * TA_BATCH;
  const f16* mV = ws + MV_OFF + (size_t)b * MV_BATCH;
  const int pa = rb * 2;        // A panel base (16-row panels)

  // ---------------- Phase 1: S = M[q0..q0+31] . M^T ----------------
  {
    f32x4 acc[2][8] = {};       // 64 acc regs; wave w -> cols w*128..w*128+127
    for (int kc = 0; kc < 24; ++kc) {
      half8 afr[2], bfr[8];
#pragma unroll
      for (int rf = 0; rf < 2; ++rf)
        afr[rf] = *(const half8*)(mA + ((size_t)(pa + rf) * 24 + kc) * 512 + lane * 8);
#pragma unroll
      for (int cf = 0; cf < 8; ++cf)
        bfr[cf] = *(const half8*)(mA + ((size_t)(w * 8 + cf) * 24 + kc) * 512 + lane * 8);
#pragma unroll
      for (int rf = 0; rf < 2; ++rf)
#pragma unroll
        for (int cf = 0; cf < 8; ++cf)
          acc[rf][cf] = __builtin_amdgcn_mfma_f32_16x16x32_f16(afr[rf], bfr[cf], acc[rf][cf], 0, 0, 0);
    }
    { // tail chunk k=768..783 (zero for l4>=2)
      half8 afr[2], bfr[8];
#pragma unroll
      for (int rf = 0; rf < 2; ++rf) {
        half8 v = {};
        if (l4 < 2) v = *(const half8*)(tA + (pa + rf) * 256 + lane * 8);
        afr[rf] = v;
      }
#pragma unroll
      for (int cf = 0; cf < 8; ++cf) {
        half8 v = {};
        if (l4 < 2) v = *(const half8*)(tA + (w * 8 + cf) * 256 + lane * 8);
        bfr[cf] = v;
      }
#pragma unroll
      for (int rf = 0; rf < 2; ++rf)
#pragma unroll
        for (int cf = 0; cf < 8; ++cf)
          acc[rf][cf] = __builtin_amdgcn_mfma_f32_16x16x32_f16(afr[rf], bfr[cf], acc[rf][cf], 0, 0, 0);
    }
    // raw scores -> LDS (XOR swizzle (row&7)<<4)
#pragma unroll
    for (int rf = 0; rf < 2; ++rf)
#pragma unroll
      for (int cf = 0; cf < 8; ++cf)
#pragma unroll
        for (int r = 0; r < 4; ++r) {
          const int row = rf * 16 + l4 * 4 + r;     // 0..31
          const int col = w * 128 + cf * 16 + l15;
          int byte = row * 2048 + col * 2;
          byte ^= (row & 7) << 4;
          *(f16*)(Pb + byte) = (f16)acc[rf][cf][r];
        }
  }
  __syncthreads();

  // ---------------- softmax, rows w*4..w*4+3 (lane-consecutive 16B) ----------------
  {
    const float ksc = 0.045084223f;   // log2(e)/32
    for (int rr = 0; rr < 4; ++rr) {
      const int row = w * 4 + rr;
      const int sw  = (row & 7) << 4;
      char* rbase = Pb + row * 2048;
      const int p0 = (lane * 16) ^ sw;
      half8 v0 = *(half8*)(rbase + p0);
      half8 v1 = *(half8*)(rbase + 1024 + p0);
      float f[16];
#pragma unroll
      for (int e = 0; e < 8; ++e) { f[e] = (float)v0[e]; f[e+8] = (float)v1[e]; }
      float mx = f[0];
#pragma unroll
      for (int e = 1; e < 16; ++e) mx = fmaxf(mx, f[e]);
      for (int d = 1; d < 64; d <<= 1) mx = fmaxf(mx, __shfl_xor(mx, d));
      float sum = 0.f;
#pragma unroll
      for (int e = 0; e < 16; ++e) { f[e] = exp2f((f[e] - mx) * ksc); sum += f[e]; }
      for (int d = 1; d < 64; d <<= 1) sum += __shfl_xor(sum, d);
      const float inv = 1.f / sum;
#pragma unroll
      for (int e = 0; e < 8; ++e) { v0[e] = (f16)(f[e]*inv); v1[e] = (f16)(f[e+8]*inv); }
      *(half8*)(rbase + p0) = v0;
      *(half8*)(rbase + 1024 + p0) = v1;
    }
  }
  __syncthreads();

  // ---------------- Phase 2: y = P . V ; out = x + y (t outer) ----------------
  {
    f32x4 a2[7][2] = {};   // [si][rf]; strips s = w + 8*si over 49
    for (int t = 0; t < 16; ++t) {
      half8 afr[2][2];
#pragma unroll
      for (int rf = 0; rf < 2; ++rf)
#pragma unroll
        for (int kf = 0; kf < 2; ++kf) {
          const int row = rf * 16 + l15;            // A: row=lane&15, k=(lane>>4)*8+e
          int byte = row * 2048 + t * 128 + kf * 64 + (l4 << 4);
          byte ^= (row & 7) << 4;
          afr[rf][kf] = *(half8*)(Pb + byte);
        }
#pragma unroll
      for (int si = 0; si < 7; ++si) {
        const int s = w + 8 * si;
        if (s < 49) {                               // wave-uniform
#pragma unroll
          for (int kf = 0; kf < 2; ++kf) {
            const half8 bfr = *(const half8*)(mV + ((size_t)s * 32 + t * 2 + kf) * 512 + lane * 8);
#pragma unroll
            for (int rf = 0; rf < 2; ++rf)
              a2[si][rf] = __builtin_amdgcn_mfma_f32_16x16x32_f16(afr[rf][kf], bfr, a2[si][rf], 0, 0, 0);
          }
        }
      }
    }
#pragma unroll
    for (int si = 0; si < 7; ++si) {
      const int s = w + 8 * si;
      if (s < 49) {
        const int d = s * 16 + l15;
#pragma unroll
        for (int rf = 0; rf < 2; ++rf)
#pragma unroll
          for (int r = 0; r < 4; ++r) {
            const size_t idx = (size_t)(b * C_ + q0 + rf * 16 + l4 * 4 + r) * HW_ + d;
            out[idx] = x[idx] + a2[si][rf][r];
          }
      }
    }
  }
}

// ---------------------------------------------------------------------------
// Fallback (round-1 kernel): only if ws too small.
// ---------------------------------------------------------------------------
__device__ __forceinline__ half8 pack8(const float4& a, const float4& b) {
  half8 r;
  r[0]=(f16)a.x; r[1]=(f16)a.y; r[2]=(f16)a.z; r[3]=(f16)a.w;
  r[4]=(f16)b.x; r[5]=(f16)b.y; r[6]=(f16)b.z; r[7]=(f16)b.w;
  return r;
}

__global__ __launch_bounds__(512, 2)
void chanattn_fallback(const float* __restrict__ x, float* __restrict__ out) {
  __shared__ f16 Pl[64 * C_];
  const int bi   = blockIdx.x;
  const int slot = bi >> 3;
  const int b    = ((slot >> 4) << 3) | (bi & 7);
  const int rb   = slot & 15;
  const int q0   = rb * 64;
  const int tid  = threadIdx.x;
  const int w    = tid >> 6;
  const int lane = tid & 63;
  const int l15  = lane & 15;
  const int l4   = lane >> 4;
  const float* mb = x + (size_t)b * (C_ * HW_);
  char* Pb = (char*)Pl;
  {
    const int cw = w * 128;
    for (int tile = 0; tile < 2; ++tile) {
      const int c0 = cw + tile * 64;
      f32x4 acc[4][4] = {};
      for (int kc = 0; kc < 25; ++kc) {
        const int k0 = kc * 32 + l4 * 8;
        const bool ok = (k0 < HW_);
        half8 afr[4], bfr[4];
#pragma unroll
        for (int rf = 0; rf < 4; ++rf) {
          if (ok) { const float4* p = (const float4*)(mb + (q0 + rf*16 + l15) * HW_ + k0); afr[rf] = pack8(p[0], p[1]); }
          else {
#pragma unroll
            for (int e = 0; e < 8; ++e) afr[rf][e] = (f16)0.f; }
        }
#pragma unroll
        for (int cf = 0; cf < 4; ++cf) {
          if (ok) { const float4* p = (const float4*)(mb + (c0 + cf*16 + l15) * HW_ + k0); bfr[cf] = pack8(p[0], p[1]); }
          else {
#pragma unroll
            for (int e = 0; e < 8; ++e) bfr[cf][e] = (f16)0.f; }
        }
#pragma unroll
        for (int rf = 0; rf < 4; ++rf)
#pragma unroll
          for (int cf = 0; cf < 4; ++cf)
            acc[rf][cf] = __builtin_amdgcn_mfma_f32_16x16x32_f16(afr[rf], bfr[cf], acc[rf][cf], 0, 0, 0);
      }
#pragma unroll
      for (int rf = 0; rf < 4; ++rf)
#pragma unroll
        for (int cf = 0; cf < 4; ++cf)
#pragma unroll
          for (int r = 0; r < 4; ++r) {
            const int row = rf*16 + l4*4 + r;
            const int col = c0 + cf*16 + l15;
            int byte = row*2048 + col*2;
            byte ^= (row & 7) << 4;
            *(f16*)(Pb + byte) = (f16)acc[rf][cf][r];
          }
    }
  }
  __syncthreads();
  {
    const float ksc = 0.045084223f;
    for (int rr = 0; rr < 8; ++rr) {
      const int row = w*8 + rr;
      const int sw  = (row & 7) << 4;
      char* rbase = Pb + row*2048;
      const int p0 = (lane * 16) ^ sw;
      half8 v0 = *(half8*)(rbase + p0);
      half8 v1 = *(half8*)(rbase + 1024 + p0);
      float f[16];
#pragma unroll
      for (int e = 0; e < 8; ++e) { f[e] = (float)v0[e]; f[e+8] = (float)v1[e]; }
      float mx = f[0];
#pragma unroll
      for (int e = 1; e < 16; ++e) mx = fmaxf(mx, f[e]);
      for (int d = 1; d < 64; d <<= 1) mx = fmaxf(mx, __shfl_xor(mx, d));
      float sum = 0.f;
#pragma unroll
      for (int e = 0; e < 16; ++e) { f[e] = exp2f((f[e] - mx) * ksc); sum += f[e]; }
      for (int d = 1; d < 64; d <<= 1) sum += __shfl_xor(sum, d);
      const float inv = 1.f / sum;
#pragma unroll
      for (int e = 0; e < 8; ++e) { v0[e] = (f16)(f[e]*inv); v1[e] = (f16)(f[e+8]*inv); }
      *(half8*)(rbase + p0) = v0;
      *(half8*)(rbase + 1024 + p0) = v1;
    }
  }
  __syncthreads();
  {
    f32x4 acc[7][4] = {};
    for (int t = 0; t < 16; ++t) {
      half8 afr[4][2];
#pragma unroll
      for (int rf = 0; rf < 4; ++rf)
#pragma unroll
        for (int kf = 0; kf < 2; ++kf) {
          const int row = rf*16 + l15;
          int byte = row*2048 + t*128 + kf*64 + l4*16;
          byte ^= (row & 7) << 4;
          afr[rf][kf] = *(half8*)(Pb + byte);
        }
#pragma unroll
      for (int si = 0; si < 7; ++si) {
        const int s = w + 8*si;
        if (s < 49) {
          const int d = s*16 + l15;
#pragma unroll
          for (int kf = 0; kf < 2; ++kf) {
            const int kv = t*64 + kf*32 + l4*8;
            half8 bfr;
#pragma unroll
            for (int e = 0; e < 8; ++e) bfr[e] = (f16)mb[(kv + e) * HW_ + d];
#pragma unroll
            for (int rf = 0; rf < 4; ++rf)
              acc[si][rf] = __builtin_amdgcn_mfma_f32_16x16x32_f16(afr[rf][kf], bfr, acc[si][rf], 0, 0, 0);
          }
        }
      }
    }
#pragma unroll
    for (int si = 0; si < 7; ++si) {
      const int s = w + 8*si;
      if (s < 49) {
        const int d = s*16 + l15;
#pragma unroll
        for (int rf = 0; rf < 4; ++rf)
#pragma unroll
          for (int r = 0; r < 4; ++r) {
            const size_t idx = (size_t)(b*C_ + q0 + rf*16 + l4*4 + r) * HW_ + d;
            out[idx] = x[idx] + acc[si][rf][r];
          }
      }
    }
  }
}

extern "C" void kernel_launch(void* const* d_in, const int* in_sizes, int n_in,
                              void* d_out, int out_size, void* d_ws, size_t ws_size,
                              hipStream_t stream) {
  const float* x = (const float*)d_in[0];
  float* out = (float*)d_out;
  if (ws_size >= WS_NEED) {
    f16* ws = (f16*)d_ws;
    prep_kernel<<<dim3(32 * 16 * 13), dim3(256), 0, stream>>>(x, ws);
    chanattn_main32<<<dim3(1024), dim3(512), 0, stream>>>(x, ws, out);
  } else {
    chanattn_fallback<<<dim3(512), dim3(512), 0, stream>>>(x, out);
  }
}